// Round 1
// baseline (736.142 us; speedup 1.0000x reference)
//
#include <hip/hip_runtime.h>

static constexpr int F1 = 256;   // input features
static constexpr int H1 = 64;    // hidden dim
static constexpr int C2 = 32;    // output classes

// ---------------- edge-index access (robust to int32 or int64 storage) -----
// If the harness stored edge_index as int64, every value < 2^31 so the odd
// 32-bit words are all zero; detect that once, branch uniformly per kernel.
__device__ __forceinline__ int ld_src(const int* __restrict__ ei, int E, int e, bool is64) {
  return is64 ? ei[2 * (size_t)e] : ei[e];
}
__device__ __forceinline__ int ld_dst(const int* __restrict__ ei, int E, int e, bool is64) {
  return is64 ? ei[2 * ((size_t)E + (size_t)e)] : ei[(size_t)E + (size_t)e];
}

__global__ __launch_bounds__(256) void k_detect(const int* __restrict__ ei, unsigned* __restrict__ flag) {
  __shared__ int nz;
  if (threadIdx.x == 0) nz = 0;
  __syncthreads();
  // sample odd 32-bit words in the first 4096 words (valid either way)
  for (int i = threadIdx.x; i < 2048; i += 256) {
    if (ei[2 * i + 1] != 0) nz = 1;  // benign race
  }
  __syncthreads();
  if (threadIdx.x == 0) flag[0] = (nz == 0) ? 1u : 0u;  // 1 => int64 layout
}

// ---------------- degree / normalization -----------------------------------
__global__ __launch_bounds__(256) void k_deg_init(unsigned* __restrict__ deg, int n) {
  int i = blockIdx.x * 256 + threadIdx.x;
  if (i < n) deg[i] = 1u;  // self-loop
}

__global__ __launch_bounds__(256) void k_deg_count(const int* __restrict__ ei, int E,
                                                   const unsigned* __restrict__ flag,
                                                   unsigned* __restrict__ deg) {
  const bool is64 = flag[0] != 0;
  int e = blockIdx.x * 256 + threadIdx.x;
  if (e < E) atomicAdd(&deg[ld_dst(ei, E, e, is64)], 1u);
}

__global__ __launch_bounds__(256) void k_dis(const unsigned* __restrict__ deg,
                                             float* __restrict__ dis, int n) {
  int i = blockIdx.x * 256 + threadIdx.x;
  if (i < n) dis[i] = 1.0f / sqrtf((float)deg[i]);  // deg >= 1 always
}

// ---------------- GEMM1: xw1 = x @ W1   (N x 256) @ (256 x 64) --------------
// 16 rows/block, 256 threads: col = tid&63, row-group = tid>>6 handles 4 rows.
// W staged in LDS in two 32KB halves; x tile (16KB) staged once.
__global__ __launch_bounds__(256) void k_gemm1(const float* __restrict__ x,
                                               const float* __restrict__ W,
                                               float* __restrict__ y, int n) {
  __shared__ __align__(16) float wl[(F1 / 2) * H1];  // 32 KB
  __shared__ __align__(16) float xl[16 * F1];        // 16 KB
  const int tid = threadIdx.x;
  const int row0 = blockIdx.x * 16;
  const int rv = min(16, n - row0);

  // stage x tile (contiguous rows) as float4
  const float4* __restrict__ xg = reinterpret_cast<const float4*>(x + (size_t)row0 * F1);
  float4* xl4 = reinterpret_cast<float4*>(xl);
  for (int i = tid; i < rv * (F1 / 4); i += 256) xl4[i] = xg[i];

  const int col = tid & 63;
  const int rq = tid >> 6;  // 0..3
  const float* xr0 = &xl[(rq * 4 + 0) * F1];
  const float* xr1 = &xl[(rq * 4 + 1) * F1];
  const float* xr2 = &xl[(rq * 4 + 2) * F1];
  const float* xr3 = &xl[(rq * 4 + 3) * F1];
  float acc0 = 0.f, acc1 = 0.f, acc2 = 0.f, acc3 = 0.f;

  for (int half = 0; half < 2; ++half) {
    if (half) __syncthreads();  // protect wl reuse
    for (int i = tid; i < (F1 / 2) * H1; i += 256) wl[i] = W[half * (F1 / 2) * H1 + i];
    __syncthreads();
    const int k0 = half * (F1 / 2);
#pragma unroll 4
    for (int k = 0; k < F1 / 2; k += 4) {
      float4 a0 = *reinterpret_cast<const float4*>(xr0 + k0 + k);
      float4 a1 = *reinterpret_cast<const float4*>(xr1 + k0 + k);
      float4 a2 = *reinterpret_cast<const float4*>(xr2 + k0 + k);
      float4 a3 = *reinterpret_cast<const float4*>(xr3 + k0 + k);
      const float* wp = &wl[k * H1 + col];
      float w0 = wp[0];
      float w1 = wp[H1];
      float w2 = wp[2 * H1];
      float w3 = wp[3 * H1];
      acc0 = fmaf(a0.x, w0, fmaf(a0.y, w1, fmaf(a0.z, w2, fmaf(a0.w, w3, acc0))));
      acc1 = fmaf(a1.x, w0, fmaf(a1.y, w1, fmaf(a1.z, w2, fmaf(a1.w, w3, acc1))));
      acc2 = fmaf(a2.x, w0, fmaf(a2.y, w1, fmaf(a2.z, w2, fmaf(a2.w, w3, acc2))));
      acc3 = fmaf(a3.x, w0, fmaf(a3.y, w1, fmaf(a3.z, w2, fmaf(a3.w, w3, acc3))));
    }
  }

  float* yb = y + (size_t)row0 * H1;
  if (rq * 4 + 0 < rv) yb[(rq * 4 + 0) * H1 + col] = acc0;
  if (rq * 4 + 1 < rv) yb[(rq * 4 + 1) * H1 + col] = acc1;
  if (rq * 4 + 2 < rv) yb[(rq * 4 + 2) * H1 + col] = acc2;
  if (rq * 4 + 3 < rv) yb[(rq * 4 + 3) * H1 + col] = acc3;
}

// ---------------- GEMM2: xw2 = relu(agg1 + b1) @ W2  (N x 64) @ (64 x 32) ---
__global__ __launch_bounds__(256) void k_gemm2(const float* __restrict__ agg,
                                               const float* __restrict__ b1,
                                               const float* __restrict__ W,
                                               float* __restrict__ y, int n) {
  __shared__ __align__(16) float wl[H1 * C2];  // 8 KB
  __shared__ __align__(16) float hl[32 * H1];  // 8 KB
  const int tid = threadIdx.x;
  const int row0 = blockIdx.x * 32;
  const int rv = min(32, n - row0);

  for (int i = tid; i < H1 * C2; i += 256) wl[i] = W[i];
  for (int i = tid; i < rv * H1; i += 256) {
    hl[i] = fmaxf(agg[(size_t)row0 * H1 + i] + b1[i & (H1 - 1)], 0.0f);
  }
  __syncthreads();

  const int col = tid & 31;
  const int rq = tid >> 5;  // 0..7
  const float* r0 = &hl[(rq * 4 + 0) * H1];
  const float* r1 = &hl[(rq * 4 + 1) * H1];
  const float* r2 = &hl[(rq * 4 + 2) * H1];
  const float* r3 = &hl[(rq * 4 + 3) * H1];
  float acc0 = 0.f, acc1 = 0.f, acc2 = 0.f, acc3 = 0.f;
#pragma unroll
  for (int k = 0; k < H1; k += 4) {
    float4 a0 = *reinterpret_cast<const float4*>(r0 + k);
    float4 a1 = *reinterpret_cast<const float4*>(r1 + k);
    float4 a2 = *reinterpret_cast<const float4*>(r2 + k);
    float4 a3 = *reinterpret_cast<const float4*>(r3 + k);
    const float* wp = &wl[k * C2 + col];
    float w0 = wp[0];
    float w1 = wp[C2];
    float w2 = wp[2 * C2];
    float w3 = wp[3 * C2];
    acc0 = fmaf(a0.x, w0, fmaf(a0.y, w1, fmaf(a0.z, w2, fmaf(a0.w, w3, acc0))));
    acc1 = fmaf(a1.x, w0, fmaf(a1.y, w1, fmaf(a1.z, w2, fmaf(a1.w, w3, acc1))));
    acc2 = fmaf(a2.x, w0, fmaf(a2.y, w1, fmaf(a2.z, w2, fmaf(a2.w, w3, acc2))));
    acc3 = fmaf(a3.x, w0, fmaf(a3.y, w1, fmaf(a3.z, w2, fmaf(a3.w, w3, acc3))));
  }

  float* yb = y + (size_t)row0 * C2;
  if (rq * 4 + 0 < rv) yb[(rq * 4 + 0) * C2 + col] = acc0;
  if (rq * 4 + 1 < rv) yb[(rq * 4 + 1) * C2 + col] = acc1;
  if (rq * 4 + 2 < rv) yb[(rq * 4 + 2) * C2 + col] = acc2;
  if (rq * 4 + 3 < rv) yb[(rq * 4 + 3) * C2 + col] = acc3;
}

// ---------------- self-loop inits -------------------------------------------
__global__ __launch_bounds__(256) void k_selfinit1(const float* __restrict__ xw,
                                                   const float* __restrict__ dis,
                                                   float* __restrict__ agg, int n) {
  int idx = blockIdx.x * 256 + threadIdx.x;
  if (idx < n * H1) {
    int i = idx >> 6;
    float d = dis[i];
    agg[idx] = xw[idx] * d * d;
  }
}

__global__ __launch_bounds__(256) void k_selfinit2(const float* __restrict__ xw,
                                                   const float* __restrict__ dis,
                                                   const float* __restrict__ b2,
                                                   float* __restrict__ out, int n) {
  int idx = blockIdx.x * 256 + threadIdx.x;
  if (idx < n * C2) {
    int i = idx >> 5;
    int c = idx & 31;
    float d = dis[i];
    out[idx] = xw[idx] * d * d + b2[c];
  }
}

// ---------------- edge scatter (atomic) -------------------------------------
// One wave (64 lanes) per edge for layer 1: lane = column -> coalesced.
__global__ __launch_bounds__(256) void k_scatter1(const int* __restrict__ ei, int E,
                                                  const unsigned* __restrict__ flag,
                                                  const float* __restrict__ dis,
                                                  const float* __restrict__ xw,
                                                  float* __restrict__ agg) {
  const bool is64 = flag[0] != 0;
  const long long total = (long long)E * H1;
  const long long stride = (long long)gridDim.x * blockDim.x;
  for (long long idx = (long long)blockIdx.x * blockDim.x + threadIdx.x; idx < total;
       idx += stride) {
    const int e = (int)(idx >> 6);
    const int c = (int)(idx & 63);
    const int s = ld_src(ei, E, e, is64);
    const int d = ld_dst(ei, E, e, is64);
    const float w = dis[s] * dis[d];
    atomicAdd(&agg[(size_t)d * H1 + c], xw[(size_t)s * H1 + c] * w);
  }
}

// Half-wave (32 lanes) per edge for layer 2.
__global__ __launch_bounds__(256) void k_scatter2(const int* __restrict__ ei, int E,
                                                  const unsigned* __restrict__ flag,
                                                  const float* __restrict__ dis,
                                                  const float* __restrict__ xw,
                                                  float* __restrict__ out) {
  const bool is64 = flag[0] != 0;
  const long long total = (long long)E * C2;
  const long long stride = (long long)gridDim.x * blockDim.x;
  for (long long idx = (long long)blockIdx.x * blockDim.x + threadIdx.x; idx < total;
       idx += stride) {
    const int e = (int)(idx >> 5);
    const int c = (int)(idx & 31);
    const int s = ld_src(ei, E, e, is64);
    const int d = ld_dst(ei, E, e, is64);
    const float w = dis[s] * dis[d];
    atomicAdd(&out[(size_t)d * C2 + c], xw[(size_t)s * C2 + c] * w);
  }
}

// ---------------- launch -----------------------------------------------------
extern "C" void kernel_launch(void* const* d_in, const int* in_sizes, int n_in,
                              void* d_out, int out_size, void* d_ws, size_t ws_size,
                              hipStream_t stream) {
  const float* x  = (const float*)d_in[0];
  const int*   ei = (const int*)d_in[1];
  const float* W1 = (const float*)d_in[2];
  const float* b1 = (const float*)d_in[3];
  const float* W2 = (const float*)d_in[4];
  const float* b2 = (const float*)d_in[5];
  float* out = (float*)d_out;

  const int n = in_sizes[0] / F1;  // 100000
  const int E = in_sizes[1] / 2;   // 1600000

  char* ws = (char*)d_ws;
  size_t off = 0;
  auto take = [&](size_t bytes) -> void* {
    void* p = ws + off;
    off += (bytes + 255) & ~(size_t)255;
    return p;
  };
  unsigned* deg  = (unsigned*)take((size_t)n * 4);
  float*    dis  = (float*)take((size_t)n * 4);
  float*    xw1  = (float*)take((size_t)n * H1 * 4);
  float*    agg1 = (float*)take((size_t)n * H1 * 4);
  float*    xw2  = (float*)take((size_t)n * C2 * 4);
  unsigned* flag = (unsigned*)take(256);
  (void)ws_size;

  k_detect<<<1, 256, 0, stream>>>(ei, flag);
  k_deg_init<<<(n + 255) / 256, 256, 0, stream>>>(deg, n);
  k_deg_count<<<(E + 255) / 256, 256, 0, stream>>>(ei, E, flag, deg);
  k_dis<<<(n + 255) / 256, 256, 0, stream>>>(deg, dis, n);

  k_gemm1<<<(n + 15) / 16, 256, 0, stream>>>(x, W1, xw1, n);
  k_selfinit1<<<(int)(((size_t)n * H1 + 255) / 256), 256, 0, stream>>>(xw1, dis, agg1, n);
  k_scatter1<<<4096, 256, 0, stream>>>(ei, E, flag, dis, xw1, agg1);

  k_gemm2<<<(n + 31) / 32, 256, 0, stream>>>(agg1, b1, W2, xw2, n);
  k_selfinit2<<<(int)(((size_t)n * C2 + 255) / 256), 256, 0, stream>>>(xw2, dis, b2, out, n);
  k_scatter2<<<4096, 256, 0, stream>>>(ei, E, flag, dis, xw2, out);
}

// Round 2
// 500.687 us; speedup vs baseline: 1.4703x; 1.4703x over previous
//
#include <hip/hip_runtime.h>

static constexpr int F1 = 256;   // input features
static constexpr int H1 = 64;    // hidden dim
static constexpr int C2 = 32;    // output classes

// ---------------- edge-index access (robust to int32 or int64 storage) -----
__device__ __forceinline__ int ld_src(const int* __restrict__ ei, int E, int e, bool is64) {
  return is64 ? ei[2 * (size_t)e] : ei[e];
}
__device__ __forceinline__ int ld_dst(const int* __restrict__ ei, int E, int e, bool is64) {
  return is64 ? ei[2 * ((size_t)E + (size_t)e)] : ei[(size_t)E + (size_t)e];
}

__global__ __launch_bounds__(256) void k_detect(const int* __restrict__ ei, unsigned* __restrict__ flag) {
  __shared__ int nz;
  if (threadIdx.x == 0) nz = 0;
  __syncthreads();
  for (int i = threadIdx.x; i < 2048; i += 256) {
    if (ei[2 * i + 1] != 0) nz = 1;  // benign race
  }
  __syncthreads();
  if (threadIdx.x == 0) flag[0] = (nz == 0) ? 1u : 0u;  // 1 => int64 layout
}

// ---------------- degree histogram ------------------------------------------
__global__ __launch_bounds__(256) void k_deg_count(const int* __restrict__ ei, int E,
                                                   const unsigned* __restrict__ flag,
                                                   unsigned* __restrict__ deg) {
  const bool is64 = flag[0] != 0;
  int e = blockIdx.x * 256 + threadIdx.x;
  if (e < E) atomicAdd(&deg[ld_dst(ei, E, e, is64)], 1u);
}

__global__ __launch_bounds__(256) void k_dis(const unsigned* __restrict__ deg,
                                             float* __restrict__ dis, int n) {
  int i = blockIdx.x * 256 + threadIdx.x;
  if (i < n) dis[i] = 1.0f / sqrtf((float)(deg[i] + 1u));  // + self-loop
}

// ---------------- exclusive scan over deg (chunk = 1024/block) --------------
__global__ __launch_bounds__(256) void k_scan_part(const unsigned* __restrict__ deg, int n,
                                                   unsigned* __restrict__ part) {
  __shared__ unsigned s[256];
  const int base = blockIdx.x * 1024;
  unsigned v = 0;
  for (int i = threadIdx.x; i < 1024; i += 256) {
    int g = base + i;
    v += (g < n) ? deg[g] : 0u;
  }
  s[threadIdx.x] = v;
  __syncthreads();
  for (int o = 128; o > 0; o >>= 1) {
    if (threadIdx.x < o) s[threadIdx.x] += s[threadIdx.x + o];
    __syncthreads();
  }
  if (threadIdx.x == 0) part[blockIdx.x] = s[0];
}

__global__ __launch_bounds__(64) void k_scan_top(unsigned* __restrict__ part, int np) {
  if (threadIdx.x == 0) {
    unsigned acc = 0;
    for (int i = 0; i < np; ++i) {
      unsigned t = part[i];
      part[i] = acc;
      acc += t;
    }
  }
}

__global__ __launch_bounds__(256) void k_scan_down(const unsigned* __restrict__ deg, int n,
                                                   const unsigned* __restrict__ part,
                                                   unsigned* __restrict__ off) {
  __shared__ unsigned ts[256];
  const int t = threadIdx.x;
  const int base = blockIdx.x * 1024 + t * 4;
  unsigned l0 = (base + 0 < n) ? deg[base + 0] : 0u;
  unsigned l1 = (base + 1 < n) ? deg[base + 1] : 0u;
  unsigned l2 = (base + 2 < n) ? deg[base + 2] : 0u;
  unsigned l3 = (base + 3 < n) ? deg[base + 3] : 0u;
  ts[t] = l0 + l1 + l2 + l3;
  __syncthreads();
  // Hillis-Steele inclusive scan
  for (int o = 1; o < 256; o <<= 1) {
    unsigned v = ts[t];
    unsigned add = (t >= o) ? ts[t - o] : 0u;
    __syncthreads();
    ts[t] = v + add;
    __syncthreads();
  }
  unsigned prefix = ((t > 0) ? ts[t - 1] : 0u) + part[blockIdx.x];
  if (base + 0 < n) off[base + 0] = prefix;
  prefix += l0;
  if (base + 1 < n) off[base + 1] = prefix;
  prefix += l1;
  if (base + 2 < n) off[base + 2] = prefix;
  prefix += l2;
  if (base + 3 < n) off[base + 3] = prefix;
}

// ---------------- bin fill ---------------------------------------------------
__global__ __launch_bounds__(256) void k_fill(const int* __restrict__ ei, int E,
                                              const unsigned* __restrict__ flag,
                                              const unsigned* __restrict__ off,
                                              unsigned* __restrict__ fill,
                                              int* __restrict__ srcbin) {
  const bool is64 = flag[0] != 0;
  int e = blockIdx.x * 256 + threadIdx.x;
  if (e < E) {
    int s = ld_src(ei, E, e, is64);
    int d = ld_dst(ei, E, e, is64);
    unsigned pos = off[d] + atomicAdd(&fill[d], 1u);
    srcbin[pos] = s;
  }
}

// ---------------- GEMM1: xw1 = x @ W1   (N x 256) @ (256 x 64) --------------
__global__ __launch_bounds__(256) void k_gemm1(const float* __restrict__ x,
                                               const float* __restrict__ W,
                                               float* __restrict__ y, int n) {
  __shared__ __align__(16) float wl[(F1 / 2) * H1];  // 32 KB
  __shared__ __align__(16) float xl[16 * F1];        // 16 KB
  const int tid = threadIdx.x;
  const int row0 = blockIdx.x * 16;
  const int rv = min(16, n - row0);

  const float4* __restrict__ xg = reinterpret_cast<const float4*>(x + (size_t)row0 * F1);
  float4* xl4 = reinterpret_cast<float4*>(xl);
  for (int i = tid; i < rv * (F1 / 4); i += 256) xl4[i] = xg[i];

  const int col = tid & 63;
  const int rq = tid >> 6;  // 0..3
  const float* xr0 = &xl[(rq * 4 + 0) * F1];
  const float* xr1 = &xl[(rq * 4 + 1) * F1];
  const float* xr2 = &xl[(rq * 4 + 2) * F1];
  const float* xr3 = &xl[(rq * 4 + 3) * F1];
  float acc0 = 0.f, acc1 = 0.f, acc2 = 0.f, acc3 = 0.f;

  for (int half = 0; half < 2; ++half) {
    if (half) __syncthreads();
    for (int i = tid; i < (F1 / 2) * H1; i += 256) wl[i] = W[half * (F1 / 2) * H1 + i];
    __syncthreads();
    const int k0 = half * (F1 / 2);
#pragma unroll 4
    for (int k = 0; k < F1 / 2; k += 4) {
      float4 a0 = *reinterpret_cast<const float4*>(xr0 + k0 + k);
      float4 a1 = *reinterpret_cast<const float4*>(xr1 + k0 + k);
      float4 a2 = *reinterpret_cast<const float4*>(xr2 + k0 + k);
      float4 a3 = *reinterpret_cast<const float4*>(xr3 + k0 + k);
      const float* wp = &wl[k * H1 + col];
      float w0 = wp[0];
      float w1 = wp[H1];
      float w2 = wp[2 * H1];
      float w3 = wp[3 * H1];
      acc0 = fmaf(a0.x, w0, fmaf(a0.y, w1, fmaf(a0.z, w2, fmaf(a0.w, w3, acc0))));
      acc1 = fmaf(a1.x, w0, fmaf(a1.y, w1, fmaf(a1.z, w2, fmaf(a1.w, w3, acc1))));
      acc2 = fmaf(a2.x, w0, fmaf(a2.y, w1, fmaf(a2.z, w2, fmaf(a2.w, w3, acc2))));
      acc3 = fmaf(a3.x, w0, fmaf(a3.y, w1, fmaf(a3.z, w2, fmaf(a3.w, w3, acc3))));
    }
  }

  float* yb = y + (size_t)row0 * H1;
  if (rq * 4 + 0 < rv) yb[(rq * 4 + 0) * H1 + col] = acc0;
  if (rq * 4 + 1 < rv) yb[(rq * 4 + 1) * H1 + col] = acc1;
  if (rq * 4 + 2 < rv) yb[(rq * 4 + 2) * H1 + col] = acc2;
  if (rq * 4 + 3 < rv) yb[(rq * 4 + 3) * H1 + col] = acc3;
}

// ---------------- GEMM2: xw2 = relu(agg1 + b1) @ W2  (N x 64) @ (64 x 32) ---
__global__ __launch_bounds__(256) void k_gemm2(const float* __restrict__ agg,
                                               const float* __restrict__ b1,
                                               const float* __restrict__ W,
                                               float* __restrict__ y, int n) {
  __shared__ __align__(16) float wl[H1 * C2];  // 8 KB
  __shared__ __align__(16) float hl[32 * H1];  // 8 KB
  const int tid = threadIdx.x;
  const int row0 = blockIdx.x * 32;
  const int rv = min(32, n - row0);

  for (int i = tid; i < H1 * C2; i += 256) wl[i] = W[i];
  for (int i = tid; i < rv * H1; i += 256) {
    hl[i] = fmaxf(agg[(size_t)row0 * H1 + i] + b1[i & (H1 - 1)], 0.0f);
  }
  __syncthreads();

  const int col = tid & 31;
  const int rq = tid >> 5;  // 0..7
  const float* r0 = &hl[(rq * 4 + 0) * H1];
  const float* r1 = &hl[(rq * 4 + 1) * H1];
  const float* r2 = &hl[(rq * 4 + 2) * H1];
  const float* r3 = &hl[(rq * 4 + 3) * H1];
  float acc0 = 0.f, acc1 = 0.f, acc2 = 0.f, acc3 = 0.f;
#pragma unroll
  for (int k = 0; k < H1; k += 4) {
    float4 a0 = *reinterpret_cast<const float4*>(r0 + k);
    float4 a1 = *reinterpret_cast<const float4*>(r1 + k);
    float4 a2 = *reinterpret_cast<const float4*>(r2 + k);
    float4 a3 = *reinterpret_cast<const float4*>(r3 + k);
    const float* wp = &wl[k * C2 + col];
    float w0 = wp[0];
    float w1 = wp[C2];
    float w2 = wp[2 * C2];
    float w3 = wp[3 * C2];
    acc0 = fmaf(a0.x, w0, fmaf(a0.y, w1, fmaf(a0.z, w2, fmaf(a0.w, w3, acc0))));
    acc1 = fmaf(a1.x, w0, fmaf(a1.y, w1, fmaf(a1.z, w2, fmaf(a1.w, w3, acc1))));
    acc2 = fmaf(a2.x, w0, fmaf(a2.y, w1, fmaf(a2.z, w2, fmaf(a2.w, w3, acc2))));
    acc3 = fmaf(a3.x, w0, fmaf(a3.y, w1, fmaf(a3.z, w2, fmaf(a3.w, w3, acc3))));
  }

  float* yb = y + (size_t)row0 * C2;
  if (rq * 4 + 0 < rv) yb[(rq * 4 + 0) * C2 + col] = acc0;
  if (rq * 4 + 1 < rv) yb[(rq * 4 + 1) * C2 + col] = acc1;
  if (rq * 4 + 2 < rv) yb[(rq * 4 + 2) * C2 + col] = acc2;
  if (rq * 4 + 3 < rv) yb[(rq * 4 + 3) * C2 + col] = acc3;
}

// ---------------- gather layer 1: one wave per dst node, lane = column ------
// agg[d] = dis[d] * ( dis[d]*xw[d] + sum_{s in bin(d)} dis[s]*xw[s] )
__global__ __launch_bounds__(256) void k_gather1(const unsigned* __restrict__ off, int n, int E,
                                                 const int* __restrict__ srcbin,
                                                 const float* __restrict__ dis,
                                                 const float* __restrict__ xw,
                                                 float* __restrict__ agg) {
  const int w = blockIdx.x * 4 + (threadIdx.x >> 6);
  const int lane = threadIdx.x & 63;
  if (w >= n) return;
  const float dd = dis[w];
  unsigned p = off[w];
  const unsigned end = (w + 1 < n) ? off[w + 1] : (unsigned)E;
  float acc = xw[(size_t)w * H1 + lane] * dd;  // self-loop
  for (; p + 4 <= end; p += 4) {
    int s0 = srcbin[p + 0];
    int s1 = srcbin[p + 1];
    int s2 = srcbin[p + 2];
    int s3 = srcbin[p + 3];
    float d0 = dis[s0], d1 = dis[s1], d2 = dis[s2], d3 = dis[s3];
    float v0 = xw[(size_t)s0 * H1 + lane];
    float v1 = xw[(size_t)s1 * H1 + lane];
    float v2 = xw[(size_t)s2 * H1 + lane];
    float v3 = xw[(size_t)s3 * H1 + lane];
    acc = fmaf(v0, d0, acc);
    acc = fmaf(v1, d1, acc);
    acc = fmaf(v2, d2, acc);
    acc = fmaf(v3, d3, acc);
  }
  for (; p < end; ++p) {
    int s = srcbin[p];
    acc = fmaf(xw[(size_t)s * H1 + lane], dis[s], acc);
  }
  agg[(size_t)w * H1 + lane] = acc * dd;
}

// ---------------- gather layer 2: wave per node, 32 cols x 2 edge-streams ---
__global__ __launch_bounds__(256) void k_gather2(const unsigned* __restrict__ off, int n, int E,
                                                 const int* __restrict__ srcbin,
                                                 const float* __restrict__ dis,
                                                 const float* __restrict__ xw,
                                                 const float* __restrict__ b2,
                                                 float* __restrict__ out) {
  const int w = blockIdx.x * 4 + (threadIdx.x >> 6);
  const int lane = threadIdx.x & 63;
  const int c = lane & 31;
  const int h = lane >> 5;  // 0 or 1: which edge stream
  if (w >= n) return;
  const float dd = dis[w];
  const unsigned beg = off[w];
  const unsigned end = (w + 1 < n) ? off[w + 1] : (unsigned)E;
  float acc = (h == 0) ? xw[(size_t)w * C2 + c] * dd : 0.0f;  // self-loop
  for (unsigned p = beg + h; p < end; p += 2) {
    int s = srcbin[p];
    acc = fmaf(xw[(size_t)s * C2 + c], dis[s], acc);
  }
  acc += __shfl_xor(acc, 32, 64);  // combine the two edge streams
  if (h == 0) out[(size_t)w * C2 + c] = acc * dd + b2[c];
}

// ---------------- launch -----------------------------------------------------
extern "C" void kernel_launch(void* const* d_in, const int* in_sizes, int n_in,
                              void* d_out, int out_size, void* d_ws, size_t ws_size,
                              hipStream_t stream) {
  const float* x  = (const float*)d_in[0];
  const int*   ei = (const int*)d_in[1];
  const float* W1 = (const float*)d_in[2];
  const float* b1 = (const float*)d_in[3];
  const float* W2 = (const float*)d_in[4];
  const float* b2 = (const float*)d_in[5];
  float* out = (float*)d_out;

  const int n = in_sizes[0] / F1;  // 100000
  const int E = in_sizes[1] / 2;   // 1600000

  char* ws = (char*)d_ws;
  size_t woff = 0;
  auto take = [&](size_t bytes) -> void* {
    void* p = ws + woff;
    woff += (bytes + 255) & ~(size_t)255;
    return p;
  };
  unsigned* deg    = (unsigned*)take((size_t)n * 4);
  float*    dis    = (float*)take((size_t)n * 4);
  unsigned* off    = (unsigned*)take((size_t)n * 4);
  unsigned* fill   = (unsigned*)take((size_t)n * 4);
  unsigned* part   = (unsigned*)take(1024);
  unsigned* flag   = (unsigned*)take(256);
  int*      srcbin = (int*)take((size_t)E * 4);
  float*    xw1    = (float*)take((size_t)n * H1 * 4);
  float*    agg1   = (float*)take((size_t)n * H1 * 4);
  float*    xw2    = (float*)take((size_t)n * C2 * 4);
  (void)ws_size;

  const int np = (n + 1023) / 1024;  // scan chunks

  hipMemsetAsync(deg, 0, (size_t)n * 4, stream);
  hipMemsetAsync(fill, 0, (size_t)n * 4, stream);

  k_detect<<<1, 256, 0, stream>>>(ei, flag);
  k_deg_count<<<(E + 255) / 256, 256, 0, stream>>>(ei, E, flag, deg);
  k_dis<<<(n + 255) / 256, 256, 0, stream>>>(deg, dis, n);

  k_scan_part<<<np, 256, 0, stream>>>(deg, n, part);
  k_scan_top<<<1, 64, 0, stream>>>(part, np);
  k_scan_down<<<np, 256, 0, stream>>>(deg, n, part, off);
  k_fill<<<(E + 255) / 256, 256, 0, stream>>>(ei, E, flag, off, fill, srcbin);

  k_gemm1<<<(n + 15) / 16, 256, 0, stream>>>(x, W1, xw1, n);
  k_gather1<<<(n + 3) / 4, 256, 0, stream>>>(off, n, E, srcbin, dis, xw1, agg1);

  k_gemm2<<<(n + 31) / 32, 256, 0, stream>>>(agg1, b1, W2, xw2, n);
  k_gather2<<<(n + 3) / 4, 256, 0, stream>>>(off, n, E, srcbin, dis, xw2, b2, out);
}

// Round 3
// 362.720 us; speedup vs baseline: 2.0295x; 1.3804x over previous
//
#include <hip/hip_runtime.h>
#include <hip/hip_bf16.h>

static constexpr int F1 = 256;   // input features
static constexpr int H1 = 64;    // hidden dim
static constexpr int C2 = 32;    // output classes

typedef __attribute__((ext_vector_type(8))) short short8;
typedef __attribute__((ext_vector_type(4))) float f32x4;

__device__ __forceinline__ unsigned short f2b(float f) {
  __hip_bfloat16 h = __float2bfloat16(f);
  unsigned short u;
  __builtin_memcpy(&u, &h, 2);
  return u;
}
__device__ __forceinline__ float b2f(unsigned short u) {
  return __uint_as_float(((unsigned)u) << 16);
}

// ---------------- edge-index access (robust to int32 or int64 storage) -----
__device__ __forceinline__ int ld_src(const int* __restrict__ ei, int E, int e, bool is64) {
  return is64 ? ei[2 * (size_t)e] : ei[e];
}
__device__ __forceinline__ int ld_dst(const int* __restrict__ ei, int E, int e, bool is64) {
  return is64 ? ei[2 * ((size_t)E + (size_t)e)] : ei[(size_t)E + (size_t)e];
}

__global__ __launch_bounds__(256) void k_detect(const int* __restrict__ ei, unsigned* __restrict__ flag) {
  __shared__ int nz;
  if (threadIdx.x == 0) nz = 0;
  __syncthreads();
  for (int i = threadIdx.x; i < 2048; i += 256) {
    if (ei[2 * i + 1] != 0) nz = 1;  // benign race
  }
  __syncthreads();
  if (threadIdx.x == 0) flag[0] = (nz == 0) ? 1u : 0u;  // 1 => int64 layout
}

// ---------------- degree histogram ------------------------------------------
__global__ __launch_bounds__(256) void k_deg_count(const int* __restrict__ ei, int E,
                                                   const unsigned* __restrict__ flag,
                                                   unsigned* __restrict__ deg) {
  const bool is64 = flag[0] != 0;
  int e = blockIdx.x * 256 + threadIdx.x;
  if (e < E) atomicAdd(&deg[ld_dst(ei, E, e, is64)], 1u);
}

__global__ __launch_bounds__(256) void k_dis(const unsigned* __restrict__ deg,
                                             float* __restrict__ dis, int n) {
  int i = blockIdx.x * 256 + threadIdx.x;
  if (i < n) dis[i] = 1.0f / sqrtf((float)(deg[i] + 1u));  // + self-loop
}

// ---------------- exclusive scan over deg (chunk = 1024/block) --------------
__global__ __launch_bounds__(256) void k_scan_part(const unsigned* __restrict__ deg, int n,
                                                   unsigned* __restrict__ part) {
  __shared__ unsigned s[256];
  const int base = blockIdx.x * 1024;
  unsigned v = 0;
  for (int i = threadIdx.x; i < 1024; i += 256) {
    int g = base + i;
    v += (g < n) ? deg[g] : 0u;
  }
  s[threadIdx.x] = v;
  __syncthreads();
  for (int o = 128; o > 0; o >>= 1) {
    if (threadIdx.x < o) s[threadIdx.x] += s[threadIdx.x + o];
    __syncthreads();
  }
  if (threadIdx.x == 0) part[blockIdx.x] = s[0];
}

__global__ __launch_bounds__(64) void k_scan_top(unsigned* __restrict__ part, int np) {
  if (threadIdx.x == 0) {
    unsigned acc = 0;
    for (int i = 0; i < np; ++i) {
      unsigned t = part[i];
      part[i] = acc;
      acc += t;
    }
  }
}

__global__ __launch_bounds__(256) void k_scan_down(const unsigned* __restrict__ deg, int n,
                                                   const unsigned* __restrict__ part,
                                                   unsigned* __restrict__ off) {
  __shared__ unsigned ts[256];
  const int t = threadIdx.x;
  const int base = blockIdx.x * 1024 + t * 4;
  unsigned l0 = (base + 0 < n) ? deg[base + 0] : 0u;
  unsigned l1 = (base + 1 < n) ? deg[base + 1] : 0u;
  unsigned l2 = (base + 2 < n) ? deg[base + 2] : 0u;
  unsigned l3 = (base + 3 < n) ? deg[base + 3] : 0u;
  ts[t] = l0 + l1 + l2 + l3;
  __syncthreads();
  for (int o = 1; o < 256; o <<= 1) {
    unsigned v = ts[t];
    unsigned add = (t >= o) ? ts[t - o] : 0u;
    __syncthreads();
    ts[t] = v + add;
    __syncthreads();
  }
  unsigned prefix = ((t > 0) ? ts[t - 1] : 0u) + part[blockIdx.x];
  if (base + 0 < n) off[base + 0] = prefix;
  prefix += l0;
  if (base + 1 < n) off[base + 1] = prefix;
  prefix += l1;
  if (base + 2 < n) off[base + 2] = prefix;
  prefix += l2;
  if (base + 3 < n) off[base + 3] = prefix;
}

// ---------------- bin fill ---------------------------------------------------
__global__ __launch_bounds__(256) void k_fill(const int* __restrict__ ei, int E,
                                              const unsigned* __restrict__ flag,
                                              const unsigned* __restrict__ off,
                                              unsigned* __restrict__ fill,
                                              int* __restrict__ srcbin) {
  const bool is64 = flag[0] != 0;
  int e = blockIdx.x * 256 + threadIdx.x;
  if (e < E) {
    int s = ld_src(ei, E, e, is64);
    int d = ld_dst(ei, E, e, is64);
    unsigned pos = off[d] + atomicAdd(&fill[d], 1u);
    srcbin[pos] = s;
  }
}

// ---------------- GEMM1 (MFMA): xw1' = dis .* (x @ W1), bf16 out -------------
// Block: 4 waves x 32 rows = 128 rows/tile. A-frags straight from global x
// (fp32 -> bf16 in regs). W1 transposed+padded in LDS: wt[n=64][k=256+pad8].
__global__ __launch_bounds__(256) void k_gemm1(const float* __restrict__ x,
                                               const float* __restrict__ W,
                                               const float* __restrict__ dis,
                                               unsigned short* __restrict__ y,
                                               int n, int ntiles) {
  __shared__ __align__(16) unsigned short wt[64][264];  // 33.8 KB, pad 8 -> 2-way max
  const int tid = threadIdx.x;
  for (int i = tid; i < F1 * 16; i += 256) {  // 4096 float4s of W [256][64]
    int k = i >> 4;
    int c = (i & 15) * 4;
    float4 v = reinterpret_cast<const float4*>(W)[i];
    wt[c + 0][k] = f2b(v.x);
    wt[c + 1][k] = f2b(v.y);
    wt[c + 2][k] = f2b(v.z);
    wt[c + 3][k] = f2b(v.w);
  }
  __syncthreads();

  const int wq = tid >> 6, l = tid & 63;
  const int lr = l & 15, lk = l >> 4;  // lane row / k-group

  for (int t = blockIdx.x; t < ntiles; t += gridDim.x) {
    const int r0 = t * 128 + wq * 32;
    if (r0 >= n) continue;  // n % 32 == 0 -> surviving waves are full
    f32x4 acc[2][4] = {};
    const float* xr0 = x + (size_t)(r0 + lr) * F1;
    const float* xr1 = xr0 + (size_t)16 * F1;
#pragma unroll
    for (int kc = 0; kc < 8; ++kc) {
      const int kb = kc * 32 + lk * 8;
      float4 p0 = *reinterpret_cast<const float4*>(xr0 + kb);
      float4 p1 = *reinterpret_cast<const float4*>(xr0 + kb + 4);
      float4 q0 = *reinterpret_cast<const float4*>(xr1 + kb);
      float4 q1 = *reinterpret_cast<const float4*>(xr1 + kb + 4);
      short8 a0, a1;
      a0[0] = f2b(p0.x); a0[1] = f2b(p0.y); a0[2] = f2b(p0.z); a0[3] = f2b(p0.w);
      a0[4] = f2b(p1.x); a0[5] = f2b(p1.y); a0[6] = f2b(p1.z); a0[7] = f2b(p1.w);
      a1[0] = f2b(q0.x); a1[1] = f2b(q0.y); a1[2] = f2b(q0.z); a1[3] = f2b(q0.w);
      a1[4] = f2b(q1.x); a1[5] = f2b(q1.y); a1[6] = f2b(q1.z); a1[7] = f2b(q1.w);
#pragma unroll
      for (int nt = 0; nt < 4; ++nt) {
        short8 b = *reinterpret_cast<const short8*>(&wt[nt * 16 + lr][kb]);
        acc[0][nt] = __builtin_amdgcn_mfma_f32_16x16x32_bf16(a0, b, acc[0][nt], 0, 0, 0);
        acc[1][nt] = __builtin_amdgcn_mfma_f32_16x16x32_bf16(a1, b, acc[1][nt], 0, 0, 0);
      }
    }
    float dsc0[4], dsc1[4];
#pragma unroll
    for (int r = 0; r < 4; ++r) {
      dsc0[r] = dis[r0 + lk * 4 + r];
      dsc1[r] = dis[r0 + 16 + lk * 4 + r];
    }
    unsigned short* yb = y + (size_t)r0 * H1;
#pragma unroll
    for (int nt = 0; nt < 4; ++nt)
#pragma unroll
      for (int r = 0; r < 4; ++r) {
        yb[(size_t)(lk * 4 + r) * H1 + nt * 16 + lr] = f2b(acc[0][nt][r] * dsc0[r]);
        yb[(size_t)(16 + lk * 4 + r) * H1 + nt * 16 + lr] = f2b(acc[1][nt][r] * dsc1[r]);
      }
  }
}

// ---------------- gather1: agg over CSR, fused relu(+b1), bf16 in/out --------
// h[d] = relu( dis[d] * sum_{s in bin(d) U {d}} xw1'[s]  + b1 ),  xw1' pre-scaled.
__global__ __launch_bounds__(256) void k_gather1(const unsigned* __restrict__ off, int n, int E,
                                                 const int* __restrict__ srcbin,
                                                 const float* __restrict__ dis,
                                                 const unsigned short* __restrict__ xw,
                                                 const float* __restrict__ b1,
                                                 unsigned short* __restrict__ h) {
  const int w = blockIdx.x * 4 + (threadIdx.x >> 6);
  const int lane = threadIdx.x & 63;
  if (w >= n) return;
  const float dd = dis[w];
  unsigned p = off[w];
  const unsigned end = (w + 1 < n) ? off[w + 1] : (unsigned)E;
  float acc = b2f(xw[(size_t)w * H1 + lane]);  // self-loop (pre-scaled)
  for (; p + 4 <= end; p += 4) {
    int s0 = srcbin[p + 0];
    int s1 = srcbin[p + 1];
    int s2 = srcbin[p + 2];
    int s3 = srcbin[p + 3];
    float v0 = b2f(xw[(size_t)s0 * H1 + lane]);
    float v1 = b2f(xw[(size_t)s1 * H1 + lane]);
    float v2 = b2f(xw[(size_t)s2 * H1 + lane]);
    float v3 = b2f(xw[(size_t)s3 * H1 + lane]);
    acc += v0 + v1 + v2 + v3;
  }
  for (; p < end; ++p) acc += b2f(xw[(size_t)srcbin[p] * H1 + lane]);
  h[(size_t)w * H1 + lane] = f2b(fmaxf(fmaf(acc, dd, b1[lane]), 0.0f));
}

// ---------------- GEMM2 (MFMA): xw2' = dis .* (h @ W2), bf16 in/out ----------
__global__ __launch_bounds__(256) void k_gemm2(const unsigned short* __restrict__ h,
                                               const float* __restrict__ W,
                                               const float* __restrict__ dis,
                                               unsigned short* __restrict__ y,
                                               int n, int ntiles) {
  __shared__ __align__(16) unsigned short wt[32][72];  // 4.6 KB
  const int tid = threadIdx.x;
  for (int i = tid; i < H1 * 8; i += 256) {  // 512 float4s of W2 [64][32]
    int k = i >> 3;
    int c = (i & 7) * 4;
    float4 v = reinterpret_cast<const float4*>(W)[i];
    wt[c + 0][k] = f2b(v.x);
    wt[c + 1][k] = f2b(v.y);
    wt[c + 2][k] = f2b(v.z);
    wt[c + 3][k] = f2b(v.w);
  }
  __syncthreads();

  const int wq = tid >> 6, l = tid & 63;
  const int lr = l & 15, lk = l >> 4;

  short8 bfrag[2][2];
#pragma unroll
  for (int kc = 0; kc < 2; ++kc)
#pragma unroll
    for (int nt = 0; nt < 2; ++nt)
      bfrag[kc][nt] = *reinterpret_cast<const short8*>(&wt[nt * 16 + lr][kc * 32 + lk * 8]);

  for (int t = blockIdx.x; t < ntiles; t += gridDim.x) {
    const int r0 = t * 128 + wq * 32;
    if (r0 >= n) continue;
    f32x4 acc[2][2] = {};
    const unsigned short* h0 = h + (size_t)(r0 + lr) * H1;
    const unsigned short* h1 = h0 + (size_t)16 * H1;
#pragma unroll
    for (int kc = 0; kc < 2; ++kc) {
      const int kb = kc * 32 + lk * 8;
      short8 a0 = *reinterpret_cast<const short8*>(h0 + kb);
      short8 a1 = *reinterpret_cast<const short8*>(h1 + kb);
#pragma unroll
      for (int nt = 0; nt < 2; ++nt) {
        acc[0][nt] = __builtin_amdgcn_mfma_f32_16x16x32_bf16(a0, bfrag[kc][nt], acc[0][nt], 0, 0, 0);
        acc[1][nt] = __builtin_amdgcn_mfma_f32_16x16x32_bf16(a1, bfrag[kc][nt], acc[1][nt], 0, 0, 0);
      }
    }
    float dsc0[4], dsc1[4];
#pragma unroll
    for (int r = 0; r < 4; ++r) {
      dsc0[r] = dis[r0 + lk * 4 + r];
      dsc1[r] = dis[r0 + 16 + lk * 4 + r];
    }
    unsigned short* yb = y + (size_t)r0 * C2;
#pragma unroll
    for (int nt = 0; nt < 2; ++nt)
#pragma unroll
      for (int r = 0; r < 4; ++r) {
        yb[(size_t)(lk * 4 + r) * C2 + nt * 16 + lr] = f2b(acc[0][nt][r] * dsc0[r]);
        yb[(size_t)(16 + lk * 4 + r) * C2 + nt * 16 + lr] = f2b(acc[1][nt][r] * dsc1[r]);
      }
  }
}

// ---------------- gather2: final aggregation, +b2, fp32 out ------------------
__global__ __launch_bounds__(256) void k_gather2(const unsigned* __restrict__ off, int n, int E,
                                                 const int* __restrict__ srcbin,
                                                 const float* __restrict__ dis,
                                                 const unsigned short* __restrict__ xw,
                                                 const float* __restrict__ b2,
                                                 float* __restrict__ out) {
  const int w = blockIdx.x * 4 + (threadIdx.x >> 6);
  const int lane = threadIdx.x & 63;
  const int c = lane & 31;
  const int hs = lane >> 5;  // 2 edge streams
  if (w >= n) return;
  const float dd = dis[w];
  const unsigned beg = off[w];
  const unsigned end = (w + 1 < n) ? off[w + 1] : (unsigned)E;
  float acc = (hs == 0) ? b2f(xw[(size_t)w * C2 + c]) : 0.0f;  // self-loop
  unsigned p = beg + hs;
  for (; p + 4 <= end; p += 4) {
    int s0 = srcbin[p];
    int s1 = srcbin[p + 2];
    acc += b2f(xw[(size_t)s0 * C2 + c]) + b2f(xw[(size_t)s1 * C2 + c]);
  }
  for (; p < end; p += 2) acc += b2f(xw[(size_t)srcbin[p] * C2 + c]);
  acc += __shfl_xor(acc, 32, 64);
  if (hs == 0) out[(size_t)w * C2 + c] = fmaf(acc, dd, b2[c]);
}

// ---------------- launch -----------------------------------------------------
extern "C" void kernel_launch(void* const* d_in, const int* in_sizes, int n_in,
                              void* d_out, int out_size, void* d_ws, size_t ws_size,
                              hipStream_t stream) {
  const float* x  = (const float*)d_in[0];
  const int*   ei = (const int*)d_in[1];
  const float* W1 = (const float*)d_in[2];
  const float* b1 = (const float*)d_in[3];
  const float* W2 = (const float*)d_in[4];
  const float* b2 = (const float*)d_in[5];
  float* out = (float*)d_out;

  const int n = in_sizes[0] / F1;  // 100000
  const int E = in_sizes[1] / 2;   // 1600000

  char* ws = (char*)d_ws;
  size_t woff = 0;
  auto take = [&](size_t bytes) -> void* {
    void* p = ws + woff;
    woff += (bytes + 255) & ~(size_t)255;
    return p;
  };
  unsigned*       deg    = (unsigned*)take((size_t)n * 4);
  float*          dis    = (float*)take((size_t)n * 4);
  unsigned*       off    = (unsigned*)take((size_t)n * 4);
  unsigned*       fill   = (unsigned*)take((size_t)n * 4);
  unsigned*       part   = (unsigned*)take(1024);
  unsigned*       flag   = (unsigned*)take(256);
  int*            srcbin = (int*)take((size_t)E * 4);
  unsigned short* xw1    = (unsigned short*)take((size_t)n * H1 * 2);
  unsigned short* h      = (unsigned short*)take((size_t)n * H1 * 2);
  unsigned short* xw2    = (unsigned short*)take((size_t)n * C2 * 2);
  (void)ws_size;

  const int np = (n + 1023) / 1024;
  const int ntiles = (n + 127) / 128;

  hipMemsetAsync(deg, 0, (size_t)n * 4, stream);
  hipMemsetAsync(fill, 0, (size_t)n * 4, stream);

  k_detect<<<1, 256, 0, stream>>>(ei, flag);
  k_deg_count<<<(E + 255) / 256, 256, 0, stream>>>(ei, E, flag, deg);
  k_dis<<<(n + 255) / 256, 256, 0, stream>>>(deg, dis, n);

  k_scan_part<<<np, 256, 0, stream>>>(deg, n, part);
  k_scan_top<<<1, 64, 0, stream>>>(part, np);
  k_scan_down<<<np, 256, 0, stream>>>(deg, n, part, off);
  k_fill<<<(E + 255) / 256, 256, 0, stream>>>(ei, E, flag, off, fill, srcbin);

  k_gemm1<<<512, 256, 0, stream>>>(x, W1, dis, xw1, n, ntiles);
  k_gather1<<<(n + 3) / 4, 256, 0, stream>>>(off, n, E, srcbin, dis, xw1, b1, h);

  k_gemm2<<<512, 256, 0, stream>>>(h, W2, dis, xw2, n, ntiles);
  k_gather2<<<(n + 3) / 4, 256, 0, stream>>>(off, n, E, srcbin, dis, xw2, b2, out);
}